// Round 8
// baseline (1561.166 us; speedup 1.0000x reference)
//
#include <hip/hip_runtime.h>
#include <hip/hip_bf16.h>
#include <math.h>

#define NN   50000
#define EE   800000
#define RREL 16
#define LLAY 5
#define NBINS (NN * RREL)

typedef __attribute__((ext_vector_type(8))) short s8v;
typedef __attribute__((ext_vector_type(4))) float f4v;

__device__ __forceinline__ unsigned short f2bf(float f) {
  __hip_bfloat16 h = __float2bfloat16(f);
  return __builtin_bit_cast(unsigned short, h);
}
__device__ __forceinline__ float bf2f(unsigned int u) {
  return __builtin_bit_cast(float, u << 16);
}
__device__ __forceinline__ void split1(float v, unsigned short& h, unsigned short& l) {
  __hip_bfloat16 hb = __float2bfloat16(v);
  float hf = __bfloat162float(hb);
  h = __builtin_bit_cast(unsigned short, hb);
  __hip_bfloat16 lb = __float2bfloat16(v - hf);
  l = __builtin_bit_cast(unsigned short, lb);
}

// ---------------- build xh0 = bf16([obj_emb[objs] | attr_emb[attributes]]) ----------------
__global__ void build_x0_kernel(const int* __restrict__ objs, const int* __restrict__ attrs,
                                const float* __restrict__ obj_emb, const float* __restrict__ attr_emb,
                                unsigned short* __restrict__ xh) {
  int t = blockIdx.x * blockDim.x + threadIdx.x;
  if (t >= NN * 32) return;
  int n = t >> 5, q = t & 31;
  float4 v;
  if (q < 24) v = *(const float4*)&obj_emb[(size_t)objs[n] * 96 + q * 4];
  else        v = *(const float4*)&attr_emb[(size_t)attrs[n] * 32 + (q - 24) * 4];
  ushort4 h;
  h.x = f2bf(v.x); h.y = f2bf(v.y); h.z = f2bf(v.z); h.w = f2bf(v.w);
  *(ushort4*)&xh[(size_t)n * 128 + q * 4] = h;
}

// ---------------- bf16-convert z (N,128) and attr_emb[attrs] (N,32) ----------------
__global__ void prep_zattr(const float* __restrict__ z, const int* __restrict__ attrs,
                           const float* __restrict__ attr_emb,
                           unsigned short* __restrict__ zh, unsigned short* __restrict__ ah) {
  int t = blockIdx.x * blockDim.x + threadIdx.x;
  if (t >= NN * 40) return;
  int n = t / 40, q = t % 40;
  float4 v;
  ushort4 h;
  if (q < 32) {
    v = *(const float4*)&z[(size_t)n * 128 + q * 4];
    h.x = f2bf(v.x); h.y = f2bf(v.y); h.z = f2bf(v.z); h.w = f2bf(v.w);
    *(ushort4*)&zh[(size_t)n * 128 + q * 4] = h;
  } else {
    int qq = q - 32;
    v = *(const float4*)&attr_emb[(size_t)attrs[n] * 32 + qq * 4];
    h.x = f2bf(v.x); h.y = f2bf(v.y); h.z = f2bf(v.z); h.w = f2bf(v.w);
    *(ushort4*)&ah[(size_t)n * 32 + qq * 4] = h;
  }
}

// ---------------- count / scan / place ----------------
__global__ void count_kernel(const int* __restrict__ triples, int* __restrict__ cnt) {
  int e = blockIdx.x * 256 + threadIdx.x;
  if (e >= EE) return;
  int p = triples[e * 3 + 1], o = triples[e * 3 + 2];
  atomicAdd(&cnt[o * RREL + p], 1);
}
__global__ void scanA(const int* __restrict__ cnt, int* __restrict__ binStart,
                      int* __restrict__ partial) {
  __shared__ int buf[1024];
  int g = blockIdx.x * 1024 + threadIdx.x;
  int v = (g < NBINS) ? cnt[g] : 0;
  buf[threadIdx.x] = v;
  __syncthreads();
  for (int d = 1; d < 1024; d <<= 1) {
    int t = (threadIdx.x >= d) ? buf[threadIdx.x - d] : 0;
    __syncthreads();
    buf[threadIdx.x] += t;
    __syncthreads();
  }
  if (g < NBINS) binStart[g] = buf[threadIdx.x] - v;
  if (threadIdx.x == 1023) partial[blockIdx.x] = buf[1023];
}
__global__ void scanB(int* __restrict__ partial, int* __restrict__ binStart, int nPart) {
  __shared__ int buf[1024];
  int v = (threadIdx.x < nPart) ? partial[threadIdx.x] : 0;
  buf[threadIdx.x] = v;
  __syncthreads();
  for (int d = 1; d < 1024; d <<= 1) {
    int t = (threadIdx.x >= d) ? buf[threadIdx.x - d] : 0;
    __syncthreads();
    buf[threadIdx.x] += t;
    __syncthreads();
  }
  if (threadIdx.x < nPart) partial[threadIdx.x] = buf[threadIdx.x] - v;
  if (threadIdx.x == 1023) binStart[NBINS] = buf[1023];
}
__global__ void scanC(int* __restrict__ binStart, const int* __restrict__ partial) {
  int g = blockIdx.x * 1024 + threadIdx.x;
  if (g < NBINS) binStart[g] += partial[blockIdx.x];
}
// sD: source node ids in (o,p)-sorted order
__global__ void place_kernel(const int* __restrict__ triples,
                             const int* __restrict__ binStart, int* __restrict__ cursor,
                             int* __restrict__ sD) {
  int e = blockIdx.x * 256 + threadIdx.x;
  if (e >= EE) return;
  int s = triples[e * 3 + 0], p = triples[e * 3 + 1], o = triples[e * 3 + 2];
  int bin = o * RREL + p;
  int pos = binStart[bin] + atomicAdd(&cursor[bin], 1);
  sD[pos] = s;
}

// ---------------- weight preps (transpose + hi/lo split) ----------------
__global__ void prep_wrel(const float* __restrict__ Wrel, unsigned short* __restrict__ WThi,
                          unsigned short* __restrict__ WTlo) {
  int t = blockIdx.x * 256 + threadIdx.x;
  if (t >= LLAY * RREL * 128 * 128) return;
  int f = t & 127, k = (t >> 7) & 127, lr = t >> 14;
  float v = Wrel[((size_t)lr * 128 + k) * 128 + f];
  size_t di = ((size_t)lr * 128 + f) * 128 + k;
  split1(v, WThi[di], WTlo[di]);
}
__global__ void prep_wroot(const float* __restrict__ Wroot, unsigned short* __restrict__ hi,
                           unsigned short* __restrict__ lo) {
  int t = blockIdx.x * 256 + threadIdx.x;
  if (t >= LLAY * 128 * 128) return;
  int f = t & 127, k = (t >> 7) & 127, l = t >> 14;
  float v = Wroot[((size_t)l * 128 + k) * 128 + f];
  size_t di = ((size_t)l * 128 + f) * 128 + k;
  split1(v, hi[di], lo[di]);
}
__global__ void prep_wcat(const float* __restrict__ box_W1, const float* __restrict__ ang_W1,
                          unsigned short* __restrict__ hi, unsigned short* __restrict__ lo) {
  int t = blockIdx.x * 256 + threadIdx.x;
  if (t >= 1024 * 288) return;
  int k = t % 288, c = t / 288;
  float v;
  if (c < 512) v = box_W1[(size_t)k * 512 + c];
  else         v = (k < 256) ? ang_W1[(size_t)k * 512 + (c - 512)] : 0.f;
  split1(v, hi[(size_t)c * 288 + k], lo[(size_t)c * 288 + k]);
}
__global__ void prep_bcat(const float* __restrict__ box_b1, const float* __restrict__ ang_b1,
                          float* __restrict__ bcat) {
  int t = blockIdx.x * 256 + threadIdx.x;
  if (t >= 1024) return;
  bcat[t] = (t < 512) ? box_b1[t] : ang_b1[t - 512];
}
__global__ void prep_w2cat(const float* __restrict__ box_W2, const float* __restrict__ ang_W2,
                           unsigned short* __restrict__ hi, unsigned short* __restrict__ lo) {
  int t = blockIdx.x * 256 + threadIdx.x;
  if (t >= 32 * 1024) return;
  int k = t & 1023, c = t >> 10;
  float v = 0.f;
  if (c < 6)       { if (k < 512)  v = box_W2[(size_t)k * 6 + c]; }
  else if (c < 30) { if (k >= 512) v = ang_W2[(size_t)(k - 512) * 24 + (c - 6)]; }
  split1(v, hi[(size_t)c * 1024 + k], lo[(size_t)c * 1024 + k]);
}

// ---------------- fused RGCN layer: yh = relu( x@Wroot + sum_p mean_p(x) @ W_p + b ) ----------
// grid 782 x 256thr. Per 64-row block: 17 phases (16 relations + root), each = LDS A-tile
// (aggregated or copied) followed by 4 MFMA k-steps over hi/lo W chunks (reg-prefetched).
__global__ __launch_bounds__(256) void layer_fused(const unsigned short* __restrict__ xh,
                                                   const int* __restrict__ binStart,
                                                   const int* __restrict__ sD,
                                                   const unsigned short* __restrict__ Wh,
                                                   const unsigned short* __restrict__ Wl,
                                                   const unsigned short* __restrict__ Rh,
                                                   const unsigned short* __restrict__ Rl,
                                                   const float* __restrict__ bias,
                                                   unsigned short* __restrict__ yh) {
  __shared__ __align__(16) unsigned short As[64][136];
  __shared__ __align__(16) unsigned short Bs[2][128][40];
  const int tid = threadIdx.x;
  const int row0 = blockIdx.x * 64;
  const int wid = tid >> 6, lane = tid & 63;
  const int wcol = wid * 32;
  const int lr = lane & 15, lk = (lane >> 4) * 8;
  f4v acc[4][2] = {};

  s8v bR[4];
  const unsigned short* WHp;
  const unsigned short* WLp;
  auto loadB = [&](int k0) {
#pragma unroll
    for (int i = 0; i < 4; ++i) {
      int idx = tid + i * 256;       // 0..1023
      int hl = idx >> 9;
      int rem = idx & 511;
      int c = rem >> 2, c8 = (rem & 3) * 8;
      const unsigned short* Wp = hl ? WLp : WHp;
      bR[i] = *(const s8v*)&Wp[(size_t)c * 128 + k0 + c8];
    }
  };
  auto writeB = [&]() {
#pragma unroll
    for (int i = 0; i < 4; ++i) {
      int idx = tid + i * 256;
      int hl = idx >> 9;
      int rem = idx & 511;
      int c = rem >> 2, c8 = (rem & 3) * 8;
      *(s8v*)&Bs[hl][c][c8] = bR[i];
    }
  };

  for (int p = 0; p < 17; ++p) {
    WHp = (p < 16) ? Wh + (size_t)p * 128 * 128 : Rh;
    WLp = (p < 16) ? Wl + (size_t)p * 128 * 128 : Rl;

    __syncthreads();               // all readers of As/Bs from prev phase done
    loadB(0);                      // W chunk 0 in flight during aggregation

    if (p < 16) {
      // preload this wave's 16 bin bounds via lanes 0..31
      int bv = 0;
      {
        int r15 = lane & 15;
        int oL = row0 + wid * 16 + r15;
        int binL = (oL < NN ? oL : 0) * RREL + p + ((lane >> 4) & 1);
        if (lane < 32) bv = binStart[binL];
      }
      for (int rr = 0; rr < 16; ++rr) {
        int o = row0 + wid * 16 + rr;
        int beg = __shfl(bv, rr);
        int end = __shfl(bv, 16 + rr);
        float2 a = {0.f, 0.f};
        float w = 0.f;
        if (o < NN && end > beg) {
          w = 1.f / (float)(end - beg);
          for (int e = beg; e < end; ++e) {
            unsigned int u = *(const unsigned int*)&xh[(size_t)sD[e] * 128 + lane * 2];
            a.x += bf2f(u & 0xffffu);
            a.y += bf2f(u >> 16);
          }
        }
        unsigned int pk = (unsigned int)f2bf(a.x * w) | ((unsigned int)f2bf(a.y * w) << 16);
        *(unsigned int*)&As[wid * 16 + rr][lane * 2] = pk;
      }
    } else {
      // root phase: A tile = x rows themselves
#pragma unroll
      for (int i = 0; i < 4; ++i) {
        int idx = tid + i * 256;     // 0..1023
        int r = idx >> 4, c8 = (idx & 15) * 8;
        int n = row0 + r;
        s8v v;
        if (n < NN) v = *(const s8v*)&xh[(size_t)n * 128 + c8];
        else { s8v zz = {0, 0, 0, 0, 0, 0, 0, 0}; v = zz; }
        *(s8v*)&As[r][c8] = v;
      }
    }

    for (int k0 = 0; k0 < 128; k0 += 32) {
      __syncthreads();             // As visible (k0==0) / prev chunk's Bs readers done
      writeB();
      __syncthreads();
      if (k0 < 96) loadB(k0 + 32);

      s8v ah[4];
#pragma unroll
      for (int mf = 0; mf < 4; ++mf) ah[mf] = *(s8v*)&As[mf * 16 + lr][k0 + lk];
#pragma unroll
      for (int nf = 0; nf < 2; ++nf) {
        s8v bh_ = *(s8v*)&Bs[0][wcol + nf * 16 + lr][lk];
        s8v bl_ = *(s8v*)&Bs[1][wcol + nf * 16 + lr][lk];
#pragma unroll
        for (int mf = 0; mf < 4; ++mf) {
          acc[mf][nf] = __builtin_amdgcn_mfma_f32_16x16x32_bf16(ah[mf], bh_, acc[mf][nf], 0, 0, 0);
          acc[mf][nf] = __builtin_amdgcn_mfma_f32_16x16x32_bf16(ah[mf], bl_, acc[mf][nf], 0, 0, 0);
        }
      }
    }
  }

  // epilogue: + bias, relu, one bf16 rounding
#pragma unroll
  for (int mf = 0; mf < 4; ++mf)
#pragma unroll
    for (int nf = 0; nf < 2; ++nf) {
      int col = wcol + nf * 16 + lr;
      float b = bias[col];
      int rbase = row0 + mf * 16 + (lane >> 4) * 4;
#pragma unroll
      for (int q = 0; q < 4; ++q) {
        int rr = rbase + q;
        if (rr < NN) yh[(size_t)rr * 128 + col] = f2bf(fmaxf(acc[mf][nf][q] + b, 0.f));
      }
    }
}

// ---------------- fused MLP layer-1 (prefetch double-buffered) ----------------
__global__ __launch_bounds__(256) void mlpcat_mfma(const unsigned short* __restrict__ xh,
                                                   const unsigned short* __restrict__ zh,
                                                   const unsigned short* __restrict__ ath,
                                                   const unsigned short* __restrict__ Wh,
                                                   const unsigned short* __restrict__ Wl,
                                                   const float* __restrict__ bcat,
                                                   unsigned short* __restrict__ H) {
  __shared__ __align__(16) unsigned short As[64][40];
  __shared__ __align__(16) unsigned short Bs[2][256][40];
  const int tid = threadIdx.x;
  const int row0 = blockIdx.y * 64;
  const int cb = blockIdx.x;
  const int wid = tid >> 6, lane = tid & 63;
  const int wcol = wid * 64;
  const int lr = lane & 15, lk = (lane >> 4) * 8;
  f4v acc[4][4] = {};

  s8v aR;
  s8v bR[8];
  const int ar = tid >> 2, ac8 = (tid & 3) * 8;
  const int an = row0 + ar;

  auto loadStep = [&](int k0) {
    if (an < NN) {
      if (k0 < 128)      aR = *(const s8v*)&xh[(size_t)an * 128 + k0 + ac8];
      else if (k0 < 256) aR = *(const s8v*)&zh[(size_t)an * 128 + (k0 - 128) + ac8];
      else               aR = *(const s8v*)&ath[(size_t)an * 32 + (k0 - 256) + ac8];
    } else { s8v zz = {0, 0, 0, 0, 0, 0, 0, 0}; aR = zz; }
#pragma unroll
    for (int i = 0; i < 8; ++i) {
      int idx = tid + i * 256;
      int hl = idx >> 10;
      int rem = idx & 1023;
      int c = rem >> 2, c8 = (rem & 3) * 8;
      int gc = cb * 256 + c;
      const unsigned short* Wp = hl ? Wl : Wh;
      bR[i] = *(const s8v*)&Wp[(size_t)gc * 288 + k0 + c8];
    }
  };
  auto writeStep = [&]() {
    *(s8v*)&As[ar][ac8] = aR;
#pragma unroll
    for (int i = 0; i < 8; ++i) {
      int idx = tid + i * 256;
      int hl = idx >> 10;
      int rem = idx & 1023;
      int c = rem >> 2, c8 = (rem & 3) * 8;
      *(s8v*)&Bs[hl][c][c8] = bR[i];
    }
  };

  loadStep(0);
  for (int step = 0; step < 9; ++step) {
    __syncthreads();
    writeStep();
    __syncthreads();
    if (step < 8) loadStep((step + 1) * 32);

    s8v ah[4];
#pragma unroll
    for (int mf = 0; mf < 4; ++mf) ah[mf] = *(s8v*)&As[mf * 16 + lr][lk];
#pragma unroll
    for (int nf = 0; nf < 4; ++nf) {
      s8v bh_ = *(s8v*)&Bs[0][wcol + nf * 16 + lr][lk];
      s8v bl_ = *(s8v*)&Bs[1][wcol + nf * 16 + lr][lk];
#pragma unroll
      for (int mf = 0; mf < 4; ++mf) {
        acc[mf][nf] = __builtin_amdgcn_mfma_f32_16x16x32_bf16(ah[mf], bh_, acc[mf][nf], 0, 0, 0);
        acc[mf][nf] = __builtin_amdgcn_mfma_f32_16x16x32_bf16(ah[mf], bl_, acc[mf][nf], 0, 0, 0);
      }
    }
  }
#pragma unroll
  for (int mf = 0; mf < 4; ++mf)
#pragma unroll
    for (int nf = 0; nf < 4; ++nf) {
      int gc = cb * 256 + wcol + nf * 16 + lr;
      float b = bcat[gc];
      int rbase = row0 + mf * 16 + (lane >> 4) * 4;
#pragma unroll
      for (int q = 0; q < 4; ++q) {
        int rr = rbase + q;
        if (rr < NN) H[(size_t)rr * 1024 + gc] = f2bf(fmaxf(acc[mf][nf][q] + b, 0.f));
      }
    }
}

// ---------------- head MFMA (prefetch double-buffered) ----------------
__global__ __launch_bounds__(256) void head_mfma(const unsigned short* __restrict__ H,
                                                 const unsigned short* __restrict__ Wh,
                                                 const unsigned short* __restrict__ Wl,
                                                 float* __restrict__ logits) {
  __shared__ __align__(16) unsigned short As[256][40];
  __shared__ __align__(16) unsigned short Bs[2][32][40];
  const int tid = threadIdx.x;
  const int row0 = blockIdx.x * 256;
  const int wid = tid >> 6, lane = tid & 63;
  const int wrow = wid * 64;
  const int lr = lane & 15, lk = (lane >> 4) * 8;
  f4v acc[4][2] = {};

  s8v aR[4];
  s8v bR;
  const int br_hl = tid >> 7, br_rem = tid & 127;
  const int br_col = br_rem >> 2, br_c8 = (br_rem & 3) * 8;

  auto loadStep = [&](int k0) {
#pragma unroll
    for (int i = 0; i < 4; ++i) {
      int idx = tid + i * 256;
      int r = idx >> 2, c8 = (idx & 3) * 8;
      int n = row0 + r;
      if (n < NN) aR[i] = *(const s8v*)&H[(size_t)n * 1024 + k0 + c8];
      else { s8v zz = {0, 0, 0, 0, 0, 0, 0, 0}; aR[i] = zz; }
    }
    const unsigned short* Wp = br_hl ? Wl : Wh;
    bR = *(const s8v*)&Wp[(size_t)br_col * 1024 + k0 + br_c8];
  };
  auto writeStep = [&]() {
#pragma unroll
    for (int i = 0; i < 4; ++i) {
      int idx = tid + i * 256;
      int r = idx >> 2, c8 = (idx & 3) * 8;
      *(s8v*)&As[r][c8] = aR[i];
    }
    *(s8v*)&Bs[br_hl][br_col][br_c8] = bR;
  };

  loadStep(0);
  for (int step = 0; step < 32; ++step) {
    __syncthreads();
    writeStep();
    __syncthreads();
    if (step < 31) loadStep((step + 1) * 32);
#pragma unroll
    for (int nf = 0; nf < 2; ++nf) {
      s8v bh_ = *(s8v*)&Bs[0][nf * 16 + lr][lk];
      s8v bl_ = *(s8v*)&Bs[1][nf * 16 + lr][lk];
#pragma unroll
      for (int mf = 0; mf < 4; ++mf) {
        s8v a_ = *(s8v*)&As[wrow + mf * 16 + lr][lk];
        acc[mf][nf] = __builtin_amdgcn_mfma_f32_16x16x32_bf16(a_, bh_, acc[mf][nf], 0, 0, 0);
        acc[mf][nf] = __builtin_amdgcn_mfma_f32_16x16x32_bf16(a_, bl_, acc[mf][nf], 0, 0, 0);
      }
    }
  }
#pragma unroll
  for (int mf = 0; mf < 4; ++mf)
#pragma unroll
    for (int nf = 0; nf < 2; ++nf) {
      int col = nf * 16 + lr;
      int rbase = row0 + wrow + mf * 16 + (lane >> 4) * 4;
#pragma unroll
      for (int q = 0; q < 4; ++q) {
        int rr = rbase + q;
        if (rr < NN) logits[(size_t)rr * 32 + col] = acc[mf][nf][q];
      }
    }
}

// ---------------- head epilogue ----------------
__global__ void head_post(const float* __restrict__ logits, const float* __restrict__ box_b2,
                          const float* __restrict__ ang_b2, float* __restrict__ out) {
  int n = blockIdx.x * 256 + threadIdx.x;
  if (n >= NN) return;
  float l[32];
#pragma unroll
  for (int i = 0; i < 8; ++i)
    *(float4*)&l[i * 4] = *(const float4*)&logits[(size_t)n * 32 + i * 4];
  float* ob = out + (size_t)n * 6;
#pragma unroll
  for (int c = 0; c < 6; ++c) ob[c] = l[c] + box_b2[c];
  float a[24];
  float mx = -1e30f;
#pragma unroll
  for (int c = 0; c < 24; ++c) { a[c] = l[6 + c] + ang_b2[c]; mx = fmaxf(mx, a[c]); }
  float ssum = 0.f;
#pragma unroll
  for (int c = 0; c < 24; ++c) ssum += expf(a[c] - mx);
  float lse = mx + logf(ssum);
  float* oa = out + (size_t)NN * 6 + (size_t)n * 24;
#pragma unroll
  for (int c = 0; c < 24; ++c) oa[c] = a[c] - lse;
}

// ------------------------------------------------------------------------
extern "C" void kernel_launch(void* const* d_in, const int* in_sizes, int n_in,
                              void* d_out, int out_size, void* d_ws, size_t ws_size,
                              hipStream_t stream) {
  const float* z        = (const float*)d_in[0];
  const int*   objs     = (const int*)d_in[1];
  const int*   triples  = (const int*)d_in[2];
  const int*   attrs    = (const int*)d_in[3];
  const float* obj_emb  = (const float*)d_in[4];
  const float* attr_emb = (const float*)d_in[5];
  const float* Wrel     = (const float*)d_in[6];
  const float* Wroot    = (const float*)d_in[7];
  const float* bconv    = (const float*)d_in[8];
  const float* box_W1   = (const float*)d_in[9];
  const float* box_b1   = (const float*)d_in[10];
  const float* box_W2   = (const float*)d_in[11];
  const float* box_b2   = (const float*)d_in[12];
  const float* ang_W1   = (const float*)d_in[13];
  const float* ang_b1   = (const float*)d_in[14];
  const float* ang_W2   = (const float*)d_in[15];
  const float* ang_b2   = (const float*)d_in[16];
  float* out = (float*)d_out;

  char* base = (char*)d_ws;
  size_t cur = 0;
  auto alloc = [&](size_t bytes) -> char* {
    char* p = base + cur;
    cur += (bytes + 255) & ~(size_t)255;
    return p;
  };
  unsigned short* xA   = (unsigned short*)alloc((size_t)NN * 128 * 2);
  unsigned short* xB   = (unsigned short*)alloc((size_t)NN * 128 * 2);
  unsigned short* Hb   = (unsigned short*)alloc((size_t)NN * 1024 * 2);
  unsigned short* zhi  = (unsigned short*)alloc((size_t)NN * 128 * 2);
  unsigned short* athi = (unsigned short*)alloc((size_t)NN * 32 * 2);
  unsigned short* WThi = (unsigned short*)alloc((size_t)LLAY * RREL * 128 * 128 * 2);
  unsigned short* WTlo = (unsigned short*)alloc((size_t)LLAY * RREL * 128 * 128 * 2);
  unsigned short* WrtH = (unsigned short*)alloc((size_t)LLAY * 128 * 128 * 2);
  unsigned short* WrtL = (unsigned short*)alloc((size_t)LLAY * 128 * 128 * 2);
  unsigned short* WcH  = (unsigned short*)alloc((size_t)1024 * 288 * 2);
  unsigned short* WcL  = (unsigned short*)alloc((size_t)1024 * 288 * 2);
  unsigned short* W2H  = (unsigned short*)alloc((size_t)32 * 1024 * 2);
  unsigned short* W2L  = (unsigned short*)alloc((size_t)32 * 1024 * 2);
  float* bcat          = (float*)alloc(1024 * 4);
  float* logits        = (float*)alloc((size_t)NN * 32 * 4);
  int*   cnt      = (int*)alloc((size_t)NBINS * 4);
  int*   binStart = (int*)alloc((size_t)(NBINS + 1) * 4);
  int*   cursor   = (int*)alloc((size_t)NBINS * 4);
  int*   partial  = (int*)alloc(4096);
  int*   sD       = (int*)alloc((size_t)EE * 4);

  hipMemsetAsync(cnt, 0, (size_t)NBINS * 4, stream);
  hipMemsetAsync(cursor, 0, (size_t)NBINS * 4, stream);

  build_x0_kernel<<<(NN * 32 + 255) / 256, 256, 0, stream>>>(objs, attrs, obj_emb, attr_emb, xA);
  prep_zattr<<<(NN * 40 + 255) / 256, 256, 0, stream>>>(z, attrs, attr_emb, zhi, athi);
  count_kernel<<<(EE + 255) / 256, 256, 0, stream>>>(triples, cnt);
  const int nPart = (NBINS + 1023) / 1024;
  scanA<<<nPart, 1024, 0, stream>>>(cnt, binStart, partial);
  scanB<<<1, 1024, 0, stream>>>(partial, binStart, nPart);
  scanC<<<nPart, 1024, 0, stream>>>(binStart, partial);
  place_kernel<<<(EE + 255) / 256, 256, 0, stream>>>(triples, binStart, cursor, sD);
  prep_wrel<<<(LLAY * RREL * 128 * 128 + 255) / 256, 256, 0, stream>>>(Wrel, WThi, WTlo);
  prep_wroot<<<(LLAY * 128 * 128 + 255) / 256, 256, 0, stream>>>(Wroot, WrtH, WrtL);
  prep_wcat<<<(1024 * 288 + 255) / 256, 256, 0, stream>>>(box_W1, ang_W1, WcH, WcL);
  prep_bcat<<<4, 256, 0, stream>>>(box_b1, ang_b1, bcat);
  prep_w2cat<<<(32 * 1024 + 255) / 256, 256, 0, stream>>>(box_W2, ang_W2, W2H, W2L);

  const int rowBlocks = (NN + 63) / 64;      // 782
  unsigned short* xc = xA;
  unsigned short* xn = xB;
  for (int j = 0; j < LLAY; ++j) {
    layer_fused<<<rowBlocks, 256, 0, stream>>>(xc, binStart, sD,
                                               WThi + (size_t)j * RREL * 128 * 128,
                                               WTlo + (size_t)j * RREL * 128 * 128,
                                               WrtH + (size_t)j * 128 * 128,
                                               WrtL + (size_t)j * 128 * 128,
                                               bconv + (size_t)j * 128, xn);
    unsigned short* tmp = xc; xc = xn; xn = tmp;
  }

  mlpcat_mfma<<<dim3(4, rowBlocks), 256, 0, stream>>>(xc, zhi, athi, WcH, WcL, bcat, Hb);
  head_mfma<<<(NN + 255) / 256, 256, 0, stream>>>(Hb, W2H, W2L, logits);
  head_post<<<(NN + 255) / 256, 256, 0, stream>>>(logits, box_b2, ang_b2, out);
}

// Round 9
// 1217.278 us; speedup vs baseline: 1.2825x; 1.2825x over previous
//
#include <hip/hip_runtime.h>
#include <hip/hip_bf16.h>
#include <math.h>

#define NN   50000
#define EE   800000
#define RREL 16
#define LLAY 5
#define NBINS (NN * RREL)

typedef __attribute__((ext_vector_type(8))) short s8v;
typedef __attribute__((ext_vector_type(4))) float f4v;

__device__ __forceinline__ unsigned short f2bf(float f) {
  __hip_bfloat16 h = __float2bfloat16(f);
  return __builtin_bit_cast(unsigned short, h);
}
__device__ __forceinline__ float bf2f(unsigned int u) {
  return __builtin_bit_cast(float, u << 16);
}
__device__ __forceinline__ void split1(float v, unsigned short& h, unsigned short& l) {
  __hip_bfloat16 hb = __float2bfloat16(v);
  float hf = __bfloat162float(hb);
  h = __builtin_bit_cast(unsigned short, hb);
  __hip_bfloat16 lb = __float2bfloat16(v - hf);
  l = __builtin_bit_cast(unsigned short, lb);
}

// ---------------- build xh0 = bf16([obj_emb[objs] | attr_emb[attributes]]) ----------------
__global__ void build_x0_kernel(const int* __restrict__ objs, const int* __restrict__ attrs,
                                const float* __restrict__ obj_emb, const float* __restrict__ attr_emb,
                                unsigned short* __restrict__ xh) {
  int t = blockIdx.x * blockDim.x + threadIdx.x;
  if (t >= NN * 32) return;
  int n = t >> 5, q = t & 31;
  float4 v;
  if (q < 24) v = *(const float4*)&obj_emb[(size_t)objs[n] * 96 + q * 4];
  else        v = *(const float4*)&attr_emb[(size_t)attrs[n] * 32 + (q - 24) * 4];
  ushort4 h;
  h.x = f2bf(v.x); h.y = f2bf(v.y); h.z = f2bf(v.z); h.w = f2bf(v.w);
  *(ushort4*)&xh[(size_t)n * 128 + q * 4] = h;
}

// ---------------- bf16-convert z (N,128) and attr_emb[attrs] (N,32) ----------------
__global__ void prep_zattr(const float* __restrict__ z, const int* __restrict__ attrs,
                           const float* __restrict__ attr_emb,
                           unsigned short* __restrict__ zh, unsigned short* __restrict__ ah) {
  int t = blockIdx.x * blockDim.x + threadIdx.x;
  if (t >= NN * 40) return;
  int n = t / 40, q = t % 40;
  float4 v;
  ushort4 h;
  if (q < 32) {
    v = *(const float4*)&z[(size_t)n * 128 + q * 4];
    h.x = f2bf(v.x); h.y = f2bf(v.y); h.z = f2bf(v.z); h.w = f2bf(v.w);
    *(ushort4*)&zh[(size_t)n * 128 + q * 4] = h;
  } else {
    int qq = q - 32;
    v = *(const float4*)&attr_emb[(size_t)attrs[n] * 32 + qq * 4];
    h.x = f2bf(v.x); h.y = f2bf(v.y); h.z = f2bf(v.z); h.w = f2bf(v.w);
    *(ushort4*)&ah[(size_t)n * 32 + qq * 4] = h;
  }
}

// ---------------- count / scan / place ----------------
__global__ void count_kernel(const int* __restrict__ triples, int* __restrict__ cnt) {
  int e = blockIdx.x * 256 + threadIdx.x;
  if (e >= EE) return;
  int p = triples[e * 3 + 1], o = triples[e * 3 + 2];
  atomicAdd(&cnt[o * RREL + p], 1);
}
__global__ void scanA(const int* __restrict__ cnt, int* __restrict__ binStart,
                      int* __restrict__ partial) {
  __shared__ int buf[1024];
  int g = blockIdx.x * 1024 + threadIdx.x;
  int v = (g < NBINS) ? cnt[g] : 0;
  buf[threadIdx.x] = v;
  __syncthreads();
  for (int d = 1; d < 1024; d <<= 1) {
    int t = (threadIdx.x >= d) ? buf[threadIdx.x - d] : 0;
    __syncthreads();
    buf[threadIdx.x] += t;
    __syncthreads();
  }
  if (g < NBINS) binStart[g] = buf[threadIdx.x] - v;
  if (threadIdx.x == 1023) partial[blockIdx.x] = buf[1023];
}
__global__ void scanB(int* __restrict__ partial, int* __restrict__ binStart, int nPart) {
  __shared__ int buf[1024];
  int v = (threadIdx.x < nPart) ? partial[threadIdx.x] : 0;
  buf[threadIdx.x] = v;
  __syncthreads();
  for (int d = 1; d < 1024; d <<= 1) {
    int t = (threadIdx.x >= d) ? buf[threadIdx.x - d] : 0;
    __syncthreads();
    buf[threadIdx.x] += t;
    __syncthreads();
  }
  if (threadIdx.x < nPart) partial[threadIdx.x] = buf[threadIdx.x] - v;
  if (threadIdx.x == 1023) binStart[NBINS] = buf[1023];
}
__global__ void scanC(int* __restrict__ binStart, const int* __restrict__ partial) {
  int g = blockIdx.x * 1024 + threadIdx.x;
  if (g < NBINS) binStart[g] += partial[blockIdx.x];
}
// offD = s*2048 + p*128 (element offset into big-H); wD = 1/deg
__global__ void place_kernel(const int* __restrict__ triples, const int* __restrict__ cnt,
                             const int* __restrict__ binStart, int* __restrict__ cursor,
                             int* __restrict__ offD, float* __restrict__ wD) {
  int e = blockIdx.x * 256 + threadIdx.x;
  if (e >= EE) return;
  int s = triples[e * 3 + 0], p = triples[e * 3 + 1], o = triples[e * 3 + 2];
  int bin = o * RREL + p;
  int pos = binStart[bin] + atomicAdd(&cursor[bin], 1);
  offD[pos] = s * 2048 + p * 128;
  wD[pos] = 1.0f / (float)cnt[bin];
}

// ---------------- weight preps (transpose + hi/lo split) ----------------
__global__ void prep_wrel(const float* __restrict__ Wrel, unsigned short* __restrict__ WThi,
                          unsigned short* __restrict__ WTlo) {
  int t = blockIdx.x * 256 + threadIdx.x;
  if (t >= LLAY * RREL * 128 * 128) return;
  int f = t & 127, k = (t >> 7) & 127, lr = t >> 14;
  float v = Wrel[((size_t)lr * 128 + k) * 128 + f];
  size_t di = ((size_t)lr * 128 + f) * 128 + k;
  split1(v, WThi[di], WTlo[di]);
}
__global__ void prep_wroot(const float* __restrict__ Wroot, unsigned short* __restrict__ hi,
                           unsigned short* __restrict__ lo) {
  int t = blockIdx.x * 256 + threadIdx.x;
  if (t >= LLAY * 128 * 128) return;
  int f = t & 127, k = (t >> 7) & 127, l = t >> 14;
  float v = Wroot[((size_t)l * 128 + k) * 128 + f];
  size_t di = ((size_t)l * 128 + f) * 128 + k;
  split1(v, hi[di], lo[di]);
}
__global__ void prep_wcat(const float* __restrict__ box_W1, const float* __restrict__ ang_W1,
                          unsigned short* __restrict__ hi, unsigned short* __restrict__ lo) {
  int t = blockIdx.x * 256 + threadIdx.x;
  if (t >= 1024 * 288) return;
  int k = t % 288, c = t / 288;
  float v;
  if (c < 512) v = box_W1[(size_t)k * 512 + c];
  else         v = (k < 256) ? ang_W1[(size_t)k * 512 + (c - 512)] : 0.f;
  split1(v, hi[(size_t)c * 288 + k], lo[(size_t)c * 288 + k]);
}
__global__ void prep_bcat(const float* __restrict__ box_b1, const float* __restrict__ ang_b1,
                          float* __restrict__ bcat) {
  int t = blockIdx.x * 256 + threadIdx.x;
  if (t >= 1024) return;
  bcat[t] = (t < 512) ? box_b1[t] : ang_b1[t - 512];
}
__global__ void prep_w2cat(const float* __restrict__ box_W2, const float* __restrict__ ang_W2,
                           unsigned short* __restrict__ hi, unsigned short* __restrict__ lo) {
  int t = blockIdx.x * 256 + threadIdx.x;
  if (t >= 32 * 1024) return;
  int k = t & 1023, c = t >> 10;
  float v = 0.f;
  if (c < 6)       { if (k < 512)  v = box_W2[(size_t)k * 6 + c]; }
  else if (c < 30) { if (k >= 512) v = ang_W2[(size_t)(k - 512) * 24 + (c - 6)]; }
  split1(v, hi[(size_t)c * 1024 + k], lo[(size_t)c * 1024 + k]);
}

// ---------------- hrel MFMA: 64x256 tiles (2 rels/block), 2-product, reg-prefetch ----------
// grid (nrp, 782); cols hColBase + rp*256 .. +255; Wh/Wl index rl = rp*2 + (c>>7)
__global__ __launch_bounds__(256) void hrel_mfma(const unsigned short* __restrict__ xh,
                                                 const unsigned short* __restrict__ Bh,
                                                 const unsigned short* __restrict__ Bl,
                                                 unsigned short* __restrict__ H,
                                                 int hColBase, int hStride) {
  __shared__ __align__(16) unsigned short As[64][40];
  __shared__ __align__(16) unsigned short Bs[2][256][40];
  const int tid = threadIdx.x;
  const int rp = blockIdx.x;
  const int row0 = blockIdx.y * 64;
  const int wid = tid >> 6, lane = tid & 63;
  const int wcol = wid * 64;
  const int lr = lane & 15, lk = (lane >> 4) * 8;
  f4v acc[4][4] = {};

  s8v aR;
  s8v bR[8];
  const int ar = tid >> 2, ac8 = (tid & 3) * 8;
  const int an = row0 + ar;

  auto loadStep = [&](int k0) {
    if (an < NN) aR = *(const s8v*)&xh[(size_t)an * 128 + k0 + ac8];
    else { s8v zz = {0,0,0,0,0,0,0,0}; aR = zz; }
#pragma unroll
    for (int i = 0; i < 8; ++i) {
      int idx = tid + i * 256;          // 0..2047
      int hl = idx >> 10;
      int rem = idx & 1023;
      int c = rem >> 2, c8 = (rem & 3) * 8;
      int rl = rp * 2 + (c >> 7);
      const unsigned short* Wp = hl ? Bl : Bh;
      bR[i] = *(const s8v*)&Wp[((size_t)rl * 128 + (c & 127)) * 128 + k0 + c8];
    }
  };
  auto writeStep = [&]() {
    *(s8v*)&As[ar][ac8] = aR;
#pragma unroll
    for (int i = 0; i < 8; ++i) {
      int idx = tid + i * 256;
      int hl = idx >> 10;
      int rem = idx & 1023;
      int c = rem >> 2, c8 = (rem & 3) * 8;
      *(s8v*)&Bs[hl][c][c8] = bR[i];
    }
  };

  loadStep(0);
  for (int k0 = 0; k0 < 128; k0 += 32) {
    __syncthreads();
    writeStep();
    __syncthreads();
    if (k0 < 96) loadStep(k0 + 32);

    s8v ah[4];
#pragma unroll
    for (int mf = 0; mf < 4; ++mf) ah[mf] = *(s8v*)&As[mf * 16 + lr][lk];
#pragma unroll
    for (int nf = 0; nf < 4; ++nf) {
      s8v bh_ = *(s8v*)&Bs[0][wcol + nf * 16 + lr][lk];
      s8v bl_ = *(s8v*)&Bs[1][wcol + nf * 16 + lr][lk];
#pragma unroll
      for (int mf = 0; mf < 4; ++mf) {
        acc[mf][nf] = __builtin_amdgcn_mfma_f32_16x16x32_bf16(ah[mf], bh_, acc[mf][nf], 0, 0, 0);
        acc[mf][nf] = __builtin_amdgcn_mfma_f32_16x16x32_bf16(ah[mf], bl_, acc[mf][nf], 0, 0, 0);
      }
    }
  }

#pragma unroll
  for (int mf = 0; mf < 4; ++mf)
#pragma unroll
    for (int nf = 0; nf < 4; ++nf) {
      f4v v = acc[mf][nf];
      int rbase = row0 + mf * 16 + (lane >> 4) * 4;
      int cg = hColBase + rp * 256 + wcol + nf * 16 + lr;
#pragma unroll
      for (int q = 0; q < 4; ++q) {
        int rr = rbase + q;
        if (rr < NN) H[(size_t)rr * hStride + cg] = f2bf(v[q]);
      }
    }
}

// ---------------- root MFMA: xn(fp32) = xh @ (Wh+Wl) + bias, 2-product, reg-prefetch -------
__global__ __launch_bounds__(256) void root_mfma(const unsigned short* __restrict__ xh,
                                                 const unsigned short* __restrict__ Bh,
                                                 const unsigned short* __restrict__ Bl,
                                                 const float* __restrict__ bias,
                                                 float* __restrict__ y) {
  __shared__ __align__(16) unsigned short As[64][40];
  __shared__ __align__(16) unsigned short Bs[2][128][40];
  const int tid = threadIdx.x;
  const int row0 = blockIdx.x * 64;
  const int wid = tid >> 6, lane = tid & 63;
  const int lr = lane & 15, lk = (lane >> 4) * 8;
  const int wrow = (wid >> 1) * 32, wcol = (wid & 1) * 64;
  f4v acc[2][4] = {};

  s8v aR;
  s8v bR[4];
  const int ar = tid >> 2, ac8 = (tid & 3) * 8;
  const int an = row0 + ar;

  auto loadStep = [&](int k0) {
    if (an < NN) aR = *(const s8v*)&xh[(size_t)an * 128 + k0 + ac8];
    else { s8v zz = {0,0,0,0,0,0,0,0}; aR = zz; }
#pragma unroll
    for (int i = 0; i < 4; ++i) {
      int idx = tid + i * 256;       // 0..1023
      int hl = idx >> 9;
      int rem = idx & 511;
      int c = rem >> 2, c8 = (rem & 3) * 8;
      const unsigned short* Wp = hl ? Bl : Bh;
      bR[i] = *(const s8v*)&Wp[(size_t)c * 128 + k0 + c8];
    }
  };
  auto writeStep = [&]() {
    *(s8v*)&As[ar][ac8] = aR;
#pragma unroll
    for (int i = 0; i < 4; ++i) {
      int idx = tid + i * 256;
      int hl = idx >> 9;
      int rem = idx & 511;
      int c = rem >> 2, c8 = (rem & 3) * 8;
      *(s8v*)&Bs[hl][c][c8] = bR[i];
    }
  };

  loadStep(0);
  for (int k0 = 0; k0 < 128; k0 += 32) {
    __syncthreads();
    writeStep();
    __syncthreads();
    if (k0 < 96) loadStep(k0 + 32);
#pragma unroll
    for (int mf = 0; mf < 2; ++mf) {
      s8v ah_ = *(s8v*)&As[wrow + mf * 16 + lr][lk];
#pragma unroll
      for (int nf = 0; nf < 4; ++nf) {
        s8v bh_ = *(s8v*)&Bs[0][wcol + nf * 16 + lr][lk];
        s8v bl_ = *(s8v*)&Bs[1][wcol + nf * 16 + lr][lk];
        acc[mf][nf] = __builtin_amdgcn_mfma_f32_16x16x32_bf16(ah_, bh_, acc[mf][nf], 0, 0, 0);
        acc[mf][nf] = __builtin_amdgcn_mfma_f32_16x16x32_bf16(ah_, bl_, acc[mf][nf], 0, 0, 0);
      }
    }
  }
#pragma unroll
  for (int mf = 0; mf < 2; ++mf)
#pragma unroll
    for (int nf = 0; nf < 4; ++nf) {
      int col = wcol + nf * 16 + lr;
      float b = bias[col];
      int rbase = row0 + wrow + mf * 16 + (lane >> 4) * 4;
#pragma unroll
      for (int q = 0; q < 4; ++q) {
        int rr = rbase + q;
        if (rr < NN) y[(size_t)rr * 128 + col] = acc[mf][nf][q] + b;
      }
    }
}

// ---------------- fused MLP layer-1 (prefetch double-buffered) ----------------
__global__ __launch_bounds__(256) void mlpcat_mfma(const unsigned short* __restrict__ xh,
                                                   const unsigned short* __restrict__ zh,
                                                   const unsigned short* __restrict__ ath,
                                                   const unsigned short* __restrict__ Wh,
                                                   const unsigned short* __restrict__ Wl,
                                                   const float* __restrict__ bcat,
                                                   unsigned short* __restrict__ H) {
  __shared__ __align__(16) unsigned short As[64][40];
  __shared__ __align__(16) unsigned short Bs[2][256][40];
  const int tid = threadIdx.x;
  const int row0 = blockIdx.y * 64;
  const int cb = blockIdx.x;
  const int wid = tid >> 6, lane = tid & 63;
  const int wcol = wid * 64;
  const int lr = lane & 15, lk = (lane >> 4) * 8;
  f4v acc[4][4] = {};

  s8v aR;
  s8v bR[8];
  const int ar = tid >> 2, ac8 = (tid & 3) * 8;
  const int an = row0 + ar;

  auto loadStep = [&](int k0) {
    if (an < NN) {
      if (k0 < 128)      aR = *(const s8v*)&xh[(size_t)an * 128 + k0 + ac8];
      else if (k0 < 256) aR = *(const s8v*)&zh[(size_t)an * 128 + (k0 - 128) + ac8];
      else               aR = *(const s8v*)&ath[(size_t)an * 32 + (k0 - 256) + ac8];
    } else { s8v zz = {0, 0, 0, 0, 0, 0, 0, 0}; aR = zz; }
#pragma unroll
    for (int i = 0; i < 8; ++i) {
      int idx = tid + i * 256;
      int hl = idx >> 10;
      int rem = idx & 1023;
      int c = rem >> 2, c8 = (rem & 3) * 8;
      int gc = cb * 256 + c;
      const unsigned short* Wp = hl ? Wl : Wh;
      bR[i] = *(const s8v*)&Wp[(size_t)gc * 288 + k0 + c8];
    }
  };
  auto writeStep = [&]() {
    *(s8v*)&As[ar][ac8] = aR;
#pragma unroll
    for (int i = 0; i < 8; ++i) {
      int idx = tid + i * 256;
      int hl = idx >> 10;
      int rem = idx & 1023;
      int c = rem >> 2, c8 = (rem & 3) * 8;
      *(s8v*)&Bs[hl][c][c8] = bR[i];
    }
  };

  loadStep(0);
  for (int step = 0; step < 9; ++step) {
    __syncthreads();
    writeStep();
    __syncthreads();
    if (step < 8) loadStep((step + 1) * 32);

    s8v ah[4];
#pragma unroll
    for (int mf = 0; mf < 4; ++mf) ah[mf] = *(s8v*)&As[mf * 16 + lr][lk];
#pragma unroll
    for (int nf = 0; nf < 4; ++nf) {
      s8v bh_ = *(s8v*)&Bs[0][wcol + nf * 16 + lr][lk];
      s8v bl_ = *(s8v*)&Bs[1][wcol + nf * 16 + lr][lk];
#pragma unroll
      for (int mf = 0; mf < 4; ++mf) {
        acc[mf][nf] = __builtin_amdgcn_mfma_f32_16x16x32_bf16(ah[mf], bh_, acc[mf][nf], 0, 0, 0);
        acc[mf][nf] = __builtin_amdgcn_mfma_f32_16x16x32_bf16(ah[mf], bl_, acc[mf][nf], 0, 0, 0);
      }
    }
  }
#pragma unroll
  for (int mf = 0; mf < 4; ++mf)
#pragma unroll
    for (int nf = 0; nf < 4; ++nf) {
      int gc = cb * 256 + wcol + nf * 16 + lr;
      float b = bcat[gc];
      int rbase = row0 + mf * 16 + (lane >> 4) * 4;
#pragma unroll
      for (int q = 0; q < 4; ++q) {
        int rr = rbase + q;
        if (rr < NN) H[(size_t)rr * 1024 + gc] = f2bf(fmaxf(acc[mf][nf][q] + b, 0.f));
      }
    }
}

// ---------------- head MFMA (prefetch double-buffered) ----------------
__global__ __launch_bounds__(256) void head_mfma(const unsigned short* __restrict__ H,
                                                 const unsigned short* __restrict__ Wh,
                                                 const unsigned short* __restrict__ Wl,
                                                 float* __restrict__ logits) {
  __shared__ __align__(16) unsigned short As[256][40];
  __shared__ __align__(16) unsigned short Bs[2][32][40];
  const int tid = threadIdx.x;
  const int row0 = blockIdx.x * 256;
  const int wid = tid >> 6, lane = tid & 63;
  const int wrow = wid * 64;
  const int lr = lane & 15, lk = (lane >> 4) * 8;
  f4v acc[4][2] = {};

  s8v aR[4];
  s8v bR;
  const int br_hl = tid >> 7, br_rem = tid & 127;
  const int br_col = br_rem >> 2, br_c8 = (br_rem & 3) * 8;

  auto loadStep = [&](int k0) {
#pragma unroll
    for (int i = 0; i < 4; ++i) {
      int idx = tid + i * 256;
      int r = idx >> 2, c8 = (idx & 3) * 8;
      int n = row0 + r;
      if (n < NN) aR[i] = *(const s8v*)&H[(size_t)n * 1024 + k0 + c8];
      else { s8v zz = {0, 0, 0, 0, 0, 0, 0, 0}; aR[i] = zz; }
    }
    const unsigned short* Wp = br_hl ? Wl : Wh;
    bR = *(const s8v*)&Wp[(size_t)br_col * 1024 + k0 + br_c8];
  };
  auto writeStep = [&]() {
#pragma unroll
    for (int i = 0; i < 4; ++i) {
      int idx = tid + i * 256;
      int r = idx >> 2, c8 = (idx & 3) * 8;
      *(s8v*)&As[r][c8] = aR[i];
    }
    *(s8v*)&Bs[br_hl][br_col][br_c8] = bR;
  };

  loadStep(0);
  for (int step = 0; step < 32; ++step) {
    __syncthreads();
    writeStep();
    __syncthreads();
    if (step < 31) loadStep((step + 1) * 32);
#pragma unroll
    for (int nf = 0; nf < 2; ++nf) {
      s8v bh_ = *(s8v*)&Bs[0][nf * 16 + lr][lk];
      s8v bl_ = *(s8v*)&Bs[1][nf * 16 + lr][lk];
#pragma unroll
      for (int mf = 0; mf < 4; ++mf) {
        s8v a_ = *(s8v*)&As[wrow + mf * 16 + lr][lk];
        acc[mf][nf] = __builtin_amdgcn_mfma_f32_16x16x32_bf16(a_, bh_, acc[mf][nf], 0, 0, 0);
        acc[mf][nf] = __builtin_amdgcn_mfma_f32_16x16x32_bf16(a_, bl_, acc[mf][nf], 0, 0, 0);
      }
    }
  }
#pragma unroll
  for (int mf = 0; mf < 4; ++mf)
#pragma unroll
    for (int nf = 0; nf < 2; ++nf) {
      int col = nf * 16 + lr;
      int rbase = row0 + wrow + mf * 16 + (lane >> 4) * 4;
#pragma unroll
      for (int q = 0; q < 4; ++q) {
        int rr = rbase + q;
        if (rr < NN) logits[(size_t)rr * 32 + col] = acc[mf][nf][q];
      }
    }
}

// ---------------- head epilogue ----------------
__global__ void head_post(const float* __restrict__ logits, const float* __restrict__ box_b2,
                          const float* __restrict__ ang_b2, float* __restrict__ out) {
  int n = blockIdx.x * 256 + threadIdx.x;
  if (n >= NN) return;
  float l[32];
#pragma unroll
  for (int i = 0; i < 8; ++i)
    *(float4*)&l[i * 4] = *(const float4*)&logits[(size_t)n * 32 + i * 4];
  float* ob = out + (size_t)n * 6;
#pragma unroll
  for (int c = 0; c < 6; ++c) ob[c] = l[c] + box_b2[c];
  float a[24];
  float mx = -1e30f;
#pragma unroll
  for (int c = 0; c < 24; ++c) { a[c] = l[6 + c] + ang_b2[c]; mx = fmaxf(mx, a[c]); }
  float ssum = 0.f;
#pragma unroll
  for (int c = 0; c < 24; ++c) ssum += expf(a[c] - mx);
  float lse = mx + logf(ssum);
  float* oa = out + (size_t)NN * 6 + (size_t)n * 24;
#pragma unroll
  for (int c = 0; c < 24; ++c) oa[c] = a[c] - lse;
}

// ---------------- gather: xn[o] + sum w * H[s,p]; relu -> bf16 xh on last pass ----------------
__global__ __launch_bounds__(256) void gather_kernel(const unsigned short* __restrict__ H,
                                                     const int* __restrict__ binStart,
                                                     const int* __restrict__ offD,
                                                     const float* __restrict__ wD,
                                                     float* __restrict__ xn,
                                                     unsigned short* __restrict__ xh,
                                                     int binBase, int binSpan,
                                                     int smallMode, int doRelu) {
  int wid = threadIdx.x >> 6, lane = threadIdx.x & 63;
  int o = blockIdx.x * 4 + wid;
  if (o >= NN) return;
  int beg = binStart[o * RREL + binBase];
  int end = binStart[o * RREL + binBase + binSpan];
  float a0 = 0.f, a1 = 0.f, b0 = 0.f, b1 = 0.f;
  int i = beg;
  for (; i + 1 < end; i += 2) {
    int of1 = offD[i], of2 = offD[i + 1];
    if (smallMode) {
      of1 = ((of1 >> 11) << 10) | (of1 & 1023);
      of2 = ((of2 >> 11) << 10) | (of2 & 1023);
    }
    float w1 = wD[i], w2 = wD[i + 1];
    unsigned int u1 = *(const unsigned int*)&H[of1 + lane * 2];
    unsigned int u2 = *(const unsigned int*)&H[of2 + lane * 2];
    a0 += w1 * bf2f(u1 & 0xffffu);
    a1 += w1 * bf2f(u1 >> 16);
    b0 += w2 * bf2f(u2 & 0xffffu);
    b1 += w2 * bf2f(u2 >> 16);
  }
  if (i < end) {
    int of1 = offD[i];
    if (smallMode) of1 = ((of1 >> 11) << 10) | (of1 & 1023);
    float w1 = wD[i];
    unsigned int u1 = *(const unsigned int*)&H[of1 + lane * 2];
    a0 += w1 * bf2f(u1 & 0xffffu);
    a1 += w1 * bf2f(u1 >> 16);
  }
  a0 += b0; a1 += b1;
  float2 cur = *(float2*)&xn[(size_t)o * 128 + lane * 2];
  cur.x += a0; cur.y += a1;
  if (doRelu) {
    cur.x = fmaxf(cur.x, 0.f); cur.y = fmaxf(cur.y, 0.f);
    unsigned int pk = (unsigned int)f2bf(cur.x) | ((unsigned int)f2bf(cur.y) << 16);
    *(unsigned int*)&xh[(size_t)o * 128 + lane * 2] = pk;
  } else {
    *(float2*)&xn[(size_t)o * 128 + lane * 2] = cur;
  }
}

// ------------------------------------------------------------------------
extern "C" void kernel_launch(void* const* d_in, const int* in_sizes, int n_in,
                              void* d_out, int out_size, void* d_ws, size_t ws_size,
                              hipStream_t stream) {
  const float* z        = (const float*)d_in[0];
  const int*   objs     = (const int*)d_in[1];
  const int*   triples  = (const int*)d_in[2];
  const int*   attrs    = (const int*)d_in[3];
  const float* obj_emb  = (const float*)d_in[4];
  const float* attr_emb = (const float*)d_in[5];
  const float* Wrel     = (const float*)d_in[6];
  const float* Wroot    = (const float*)d_in[7];
  const float* bconv    = (const float*)d_in[8];
  const float* box_W1   = (const float*)d_in[9];
  const float* box_b1   = (const float*)d_in[10];
  const float* box_W2   = (const float*)d_in[11];
  const float* box_b2   = (const float*)d_in[12];
  const float* ang_W1   = (const float*)d_in[13];
  const float* ang_b1   = (const float*)d_in[14];
  const float* ang_W2   = (const float*)d_in[15];
  const float* ang_b2   = (const float*)d_in[16];
  float* out = (float*)d_out;

  // big-H (single gather pass) needs ~310 MB of workspace; fall back otherwise
  const int bigH = (ws_size >= (size_t)315 * 1000 * 1000) ? 1 : 0;
  const int hStride = bigH ? 2048 : 1024;

  char* base = (char*)d_ws;
  size_t cur = 0;
  auto alloc = [&](size_t bytes) -> char* {
    char* p = base + cur;
    cur += (bytes + 255) & ~(size_t)255;
    return p;
  };
  unsigned short* Hb   = (unsigned short*)alloc((size_t)NN * hStride * 2);
  float* xn            = (float*)alloc((size_t)NN * 128 * 4);
  unsigned short* xhi  = (unsigned short*)alloc((size_t)NN * 128 * 2);
  unsigned short* zhi  = (unsigned short*)alloc((size_t)NN * 128 * 2);
  unsigned short* athi = (unsigned short*)alloc((size_t)NN * 32 * 2);
  unsigned short* WThi = (unsigned short*)alloc((size_t)LLAY * RREL * 128 * 128 * 2);
  unsigned short* WTlo = (unsigned short*)alloc((size_t)LLAY * RREL * 128 * 128 * 2);
  unsigned short* WrtH = (unsigned short*)alloc((size_t)LLAY * 128 * 128 * 2);
  unsigned short* WrtL = (unsigned short*)alloc((size_t)LLAY * 128 * 128 * 2);
  unsigned short* WcH  = (unsigned short*)alloc((size_t)1024 * 288 * 2);
  unsigned short* WcL  = (unsigned short*)alloc((size_t)1024 * 288 * 2);
  unsigned short* W2H  = (unsigned short*)alloc((size_t)32 * 1024 * 2);
  unsigned short* W2L  = (unsigned short*)alloc((size_t)32 * 1024 * 2);
  float* bcat          = (float*)alloc(1024 * 4);
  float* logits        = (float*)alloc((size_t)NN * 32 * 4);
  int*   cnt      = (int*)alloc((size_t)NBINS * 4);
  int*   binStart = (int*)alloc((size_t)(NBINS + 1) * 4);
  int*   cursor   = (int*)alloc((size_t)NBINS * 4);
  int*   partial  = (int*)alloc(4096);
  int*   offD     = (int*)alloc((size_t)EE * 4);
  float* wD       = (float*)alloc((size_t)EE * 4);

  hipMemsetAsync(cnt, 0, (size_t)NBINS * 4, stream);
  hipMemsetAsync(cursor, 0, (size_t)NBINS * 4, stream);

  build_x0_kernel<<<(NN * 32 + 255) / 256, 256, 0, stream>>>(objs, attrs, obj_emb, attr_emb, xhi);
  prep_zattr<<<(NN * 40 + 255) / 256, 256, 0, stream>>>(z, attrs, attr_emb, zhi, athi);
  count_kernel<<<(EE + 255) / 256, 256, 0, stream>>>(triples, cnt);
  const int nPart = (NBINS + 1023) / 1024;
  scanA<<<nPart, 1024, 0, stream>>>(cnt, binStart, partial);
  scanB<<<1, 1024, 0, stream>>>(partial, binStart, nPart);
  scanC<<<nPart, 1024, 0, stream>>>(binStart, partial);
  place_kernel<<<(EE + 255) / 256, 256, 0, stream>>>(triples, cnt, binStart, cursor, offD, wD);
  prep_wrel<<<(LLAY * RREL * 128 * 128 + 255) / 256, 256, 0, stream>>>(Wrel, WThi, WTlo);
  prep_wroot<<<(LLAY * 128 * 128 + 255) / 256, 256, 0, stream>>>(Wroot, WrtH, WrtL);
  prep_wcat<<<(1024 * 288 + 255) / 256, 256, 0, stream>>>(box_W1, ang_W1, WcH, WcL);
  prep_bcat<<<4, 256, 0, stream>>>(box_b1, ang_b1, bcat);
  prep_w2cat<<<(32 * 1024 + 255) / 256, 256, 0, stream>>>(box_W2, ang_W2, W2H, W2L);

  const int rowBlocks = (NN + 63) / 64;      // 782
  for (int j = 0; j < LLAY; ++j) {
    const unsigned short* Bh = WThi + (size_t)j * RREL * 128 * 128;
    const unsigned short* Bl = WTlo + (size_t)j * RREL * 128 * 128;
    root_mfma<<<rowBlocks, 256, 0, stream>>>(xhi, WrtH + (size_t)j * 128 * 128,
                                             WrtL + (size_t)j * 128 * 128,
                                             bconv + (size_t)j * 128, xn);
    if (bigH) {
      hrel_mfma<<<dim3(8, rowBlocks), 256, 0, stream>>>(xhi, Bh, Bl, Hb, 0, 2048);
      gather_kernel<<<(NN + 3) / 4, 256, 0, stream>>>(Hb, binStart, offD, wD, xn, xhi,
                                                      0, 16, 0, 1);
    } else {
      for (int g = 0; g < 2; ++g) {
        hrel_mfma<<<dim3(4, rowBlocks), 256, 0, stream>>>(xhi, Bh + (size_t)g * 8 * 128 * 128,
                                                          Bl + (size_t)g * 8 * 128 * 128,
                                                          Hb, 0, 1024);
        gather_kernel<<<(NN + 3) / 4, 256, 0, stream>>>(Hb, binStart, offD, wD, xn, xhi,
                                                        g * 8, 8, 1, (g == 1) ? 1 : 0);
      }
    }
  }

  mlpcat_mfma<<<dim3(4, rowBlocks), 256, 0, stream>>>(xhi, zhi, athi, WcH, WcL, bcat, Hb);
  head_mfma<<<(NN + 255) / 256, 256, 0, stream>>>(Hb, W2H, W2L, logits);
  head_post<<<(NN + 255) / 256, 256, 0, stream>>>(logits, box_b2, ang_b2, out);
}